// Round 1
// baseline (1634.635 us; speedup 1.0000x reference)
//
#include <hip/hip_runtime.h>
#include <hip/hip_bf16.h>

#define B_  2
#define T_  2048
#define E_  1024
#define H_  16
#define HD_ 64
#define FF_ 4096
#define L_  4
#define M_  (B_*T_)   // 4096 tokens

typedef unsigned short u16;
typedef __attribute__((ext_vector_type(8))) short  short8;  // 8 bf16 (4 VGPRs)
typedef __attribute__((ext_vector_type(4))) float  f32x4;   // MFMA C/D frag

__device__ __forceinline__ u16 f2bf(float f) {
    union { float f; unsigned u; } v; v.f = f;
    unsigned r = (v.u + 0x7fffu + ((v.u >> 16) & 1u)) >> 16;  // RNE
    return (u16)r;
}

// ---------------------------------------------------------------------------
// Weight transpose + fp32->bf16: WT[n][k] = bf16(W[k][n]); one launch per layer
// covers Wqkv (1024x3072), Wproj (1024x1024), W1 (1024x4096), W2 (4096x1024).
// ---------------------------------------------------------------------------
__global__ __launch_bounds__(256) void transpose_weights(
    const float* __restrict__ Wqkv, const float* __restrict__ Wproj,
    const float* __restrict__ W1,   const float* __restrict__ W2,
    u16* __restrict__ WT) {
    __shared__ float tile[32][33];
    int bid = blockIdx.x;
    const float* src; u16* dst; int K, N, lt;
    if (bid < 3072)      { src = Wqkv;  dst = WT;           K = 1024; N = 3072; lt = bid;        }
    else if (bid < 4096) { src = Wproj; dst = WT + 3145728; K = 1024; N = 1024; lt = bid - 3072; }
    else if (bid < 8192) { src = W1;    dst = WT + 4194304; K = 1024; N = 4096; lt = bid - 4096; }
    else                 { src = W2;    dst = WT + 8388608; K = 4096; N = 1024; lt = bid - 8192; }
    int tpr = N >> 5;
    int ti = lt / tpr, tj = lt % tpr;
    int k0 = ti << 5, n0 = tj << 5;
    int tx = threadIdx.x & 31, ty = threadIdx.x >> 5;
    for (int i = 0; i < 4; i++) {
        int r = ty + (i << 3);
        tile[r][tx] = src[(size_t)(k0 + r) * N + n0 + tx];
    }
    __syncthreads();
    for (int i = 0; i < 4; i++) {
        int r = ty + (i << 3);
        dst[(size_t)(n0 + r) * K + k0 + tx] = f2bf(tile[tx][r]);
    }
}

// ---------------------------------------------------------------------------
// fp32 -> bf16 elementwise (vectorized)
// ---------------------------------------------------------------------------
__global__ __launch_bounds__(256) void convert_kernel(
    const float* __restrict__ in, u16* __restrict__ out, int n4) {
    int i = blockIdx.x * 256 + threadIdx.x;
    if (i < n4) {
        float4 v = ((const float4*)in)[i];
        ushort4 w;
        w.x = f2bf(v.x); w.y = f2bf(v.y); w.z = f2bf(v.z); w.w = f2bf(v.w);
        ((ushort4*)out)[i] = w;
    }
}

// ---------------------------------------------------------------------------
// MFMA GEMM: C[M][N] = A[M][K](bf16) * WT[N][K]^T(bf16) + bias
// EPI 0: out bf16 = C
// EPI 1: out f32  = C + res
// EPI 2: out bf16 = gelu_tanh(C)
// 128x128 tile, BK=32, 256 thr = 4 waves (2x2), wave = 4x4 of 16x16x32 mfma.
// LDS stride 40 bf16: 16B-aligned b128 rows, <=2-way bank conflicts on reads.
// ---------------------------------------------------------------------------
template <int EPI>
__global__ __launch_bounds__(256) void gemm_kernel(
    const u16* __restrict__ A, const u16* __restrict__ Bt,
    const float* __restrict__ bias, const float* res, void* outp,
    int M, int N, int K) {
    __shared__ u16 As[128 * 40];
    __shared__ u16 Bs[128 * 40];
    int t = threadIdx.x;
    int m0 = blockIdx.y << 7, n0 = blockIdx.x << 7;
    int wid = t >> 6, l15 = t & 15, quad = (t >> 4) & 3;
    int wr = wid >> 1, wc = wid & 1;
    f32x4 acc[4][4];
#pragma unroll
    for (int i = 0; i < 4; i++)
#pragma unroll
        for (int j = 0; j < 4; j++) acc[i][j] = (f32x4){0.f, 0.f, 0.f, 0.f};

    int srow = t >> 2, kch = (t & 3) << 3;
    for (int k0 = 0; k0 < K; k0 += 32) {
        __syncthreads();
#pragma unroll
        for (int p = 0; p < 2; p++) {
            int r = srow + (p << 6);
            *(uint4*)&As[r * 40 + kch] = *(const uint4*)&A [(size_t)(m0 + r) * K + k0 + kch];
            *(uint4*)&Bs[r * 40 + kch] = *(const uint4*)&Bt[(size_t)(n0 + r) * K + k0 + kch];
        }
        __syncthreads();
        short8 af[4], bf[4];
#pragma unroll
        for (int i = 0; i < 4; i++)
            af[i] = *(const short8*)&As[(wr * 64 + i * 16 + l15) * 40 + quad * 8];
#pragma unroll
        for (int j = 0; j < 4; j++)
            bf[j] = *(const short8*)&Bs[(wc * 64 + j * 16 + l15) * 40 + quad * 8];
#pragma unroll
        for (int i = 0; i < 4; i++)
#pragma unroll
            for (int j = 0; j < 4; j++)
                acc[i][j] = __builtin_amdgcn_mfma_f32_16x16x32_bf16(af[i], bf[j], acc[i][j], 0, 0, 0);
    }
    // epilogue: C/D layout col = lane&15, row = quad*4 + reg  [m89/m91 verified]
#pragma unroll
    for (int j = 0; j < 4; j++) {
        int gn = n0 + wc * 64 + j * 16 + l15;
        float bv = bias[gn];
#pragma unroll
        for (int i = 0; i < 4; i++) {
            int mb = m0 + wr * 64 + i * 16 + quad * 4;
#pragma unroll
            for (int r = 0; r < 4; r++) {
                size_t idx = (size_t)(mb + r) * N + gn;
                float v = acc[i][j][r] + bv;
                if (EPI == 0) {
                    ((u16*)outp)[idx] = f2bf(v);
                } else if (EPI == 1) {
                    ((float*)outp)[idx] = v + res[idx];
                } else {
                    float u  = 0.7978845608028654f * (v + 0.044715f * v * v * v);
                    float th = 1.f - 2.f / (__expf(2.f * u) + 1.f);
                    ((u16*)outp)[idx] = f2bf(0.5f * v * (1.f + th));
                }
            }
        }
    }
}

// ---------------------------------------------------------------------------
// MFMA flash attention. Block = (b, h, 64 q-rows), 4 waves x 16 q each.
// S^T = K.Q^T  (A-op = K natural [key][d], B-op = Q natural [q][d])
// online softmax state per lane (q = lane&15): m, l  (2 shuffles to reduce)
// O^T = V^T.P^T (A-op = Vt staged transposed, B-op = P via LDS round-trip)
// ---------------------------------------------------------------------------
__global__ __launch_bounds__(256) void attn_kernel(
    const u16* __restrict__ qkv, u16* __restrict__ y) {
    __shared__ u16 Qs[64 * 72];       // [q][d]   stride 72 (144B rows, 16B aligned)
    __shared__ u16 Ks[32 * 72];       // [key][d]
    __shared__ u16 Vt[64 * 40];       // [d][key] stride 40
    __shared__ u16 Pb[4 * 16 * 40];   // per-wave [q][key]

    int t = threadIdx.x;
    int q0 = blockIdx.x << 6;
    int h  = blockIdx.y;
    int b  = blockIdx.z;
    const size_t rs = 3 * E_;
    const u16* base = qkv + (size_t)b * T_ * rs;

    {   // stage Q (64 x 64 bf16)
        int row8 = t >> 3, dch = (t & 7) << 3;
#pragma unroll
        for (int p = 0; p < 2; p++) {
            int r = row8 + (p << 5);
            *(uint4*)&Qs[r * 72 + dch] =
                *(const uint4*)&base[(size_t)(q0 + r) * rs + h * 64 + dch];
        }
    }
    __syncthreads();
    int wid = t >> 6, l15 = t & 15, quad = (t >> 4) & 3;
    short8 qf0 = *(const short8*)&Qs[(wid * 16 + l15) * 72 + quad * 8];
    short8 qf1 = *(const short8*)&Qs[(wid * 16 + l15) * 72 + 32 + quad * 8];

    float m = -1e30f, l = 0.f;
    f32x4 o[4];
#pragma unroll
    for (int dt = 0; dt < 4; dt++) o[dt] = (f32x4){0.f, 0.f, 0.f, 0.f};

    int kkey = t >> 3, kch = (t & 7) << 3;   // K staging map (coalesced)
    int vkey = t & 31, vch = t >> 5;         // V staging map (transposed store)

    for (int c0 = 0; c0 < T_; c0 += 32) {
        *(uint4*)&Ks[kkey * 72 + kch] =
            *(const uint4*)&base[(size_t)(c0 + kkey) * rs + E_ + h * 64 + kch];
        {
            union { uint4 v; u16 u[8]; } vv;
            vv.v = *(const uint4*)&base[(size_t)(c0 + vkey) * rs + 2 * E_ + h * 64 + (vch << 3)];
#pragma unroll
            for (int i = 0; i < 8; i++) Vt[(vch * 8 + i) * 40 + vkey] = vv.u[i];
        }
        __syncthreads();

        f32x4 s0 = (f32x4){0.f, 0.f, 0.f, 0.f}, s1 = s0;
        {
            short8 ka;
            ka = *(const short8*)&Ks[l15 * 72 + quad * 8];
            s0 = __builtin_amdgcn_mfma_f32_16x16x32_bf16(ka, qf0, s0, 0, 0, 0);
            ka = *(const short8*)&Ks[l15 * 72 + 32 + quad * 8];
            s0 = __builtin_amdgcn_mfma_f32_16x16x32_bf16(ka, qf1, s0, 0, 0, 0);
            ka = *(const short8*)&Ks[(16 + l15) * 72 + quad * 8];
            s1 = __builtin_amdgcn_mfma_f32_16x16x32_bf16(ka, qf0, s1, 0, 0, 0);
            ka = *(const short8*)&Ks[(16 + l15) * 72 + 32 + quad * 8];
            s1 = __builtin_amdgcn_mfma_f32_16x16x32_bf16(ka, qf1, s1, 0, 0, 0);
        }
        float cm = -1e30f;
#pragma unroll
        for (int r = 0; r < 4; r++) {
            s0[r] *= 0.125f; s1[r] *= 0.125f;
            cm = fmaxf(cm, fmaxf(s0[r], s1[r]));
        }
        cm = fmaxf(cm, __shfl_xor(cm, 16));
        cm = fmaxf(cm, __shfl_xor(cm, 32));
        float mn = fmaxf(m, cm);
        float alpha = __expf(m - mn);
        float p0[4], p1[4], rsum = 0.f;
#pragma unroll
        for (int r = 0; r < 4; r++) {
            p0[r] = __expf(s0[r] - mn); rsum += p0[r];
            p1[r] = __expf(s1[r] - mn); rsum += p1[r];
        }
        rsum += __shfl_xor(rsum, 16);
        rsum += __shfl_xor(rsum, 32);
        l = l * alpha + rsum;
        m = mn;
#pragma unroll
        for (int dt = 0; dt < 4; dt++)
#pragma unroll
            for (int r = 0; r < 4; r++) o[dt][r] *= alpha;

        // P^T (C-layout) -> Pb[q][key]; LDS round-trip does the transpose
        ushort4 w;
        w.x = f2bf(p0[0]); w.y = f2bf(p0[1]); w.z = f2bf(p0[2]); w.w = f2bf(p0[3]);
        *(ushort4*)&Pb[(wid * 16 + l15) * 40 + quad * 4] = w;
        w.x = f2bf(p1[0]); w.y = f2bf(p1[1]); w.z = f2bf(p1[2]); w.w = f2bf(p1[3]);
        *(ushort4*)&Pb[(wid * 16 + l15) * 40 + 16 + quad * 4] = w;
        __threadfence_block();   // intra-wave LDS drain (lgkmcnt)

        short8 pb = *(const short8*)&Pb[(wid * 16 + l15) * 40 + quad * 8];
#pragma unroll
        for (int dt = 0; dt < 4; dt++) {
            short8 vf = *(const short8*)&Vt[(dt * 16 + l15) * 40 + quad * 8];
            o[dt] = __builtin_amdgcn_mfma_f32_16x16x32_bf16(vf, pb, o[dt], 0, 0, 0);
        }
        __syncthreads();   // protect Ks/Vt before next chunk's staging
    }
    float rl = 1.f / l;
    size_t yrow = ((size_t)b * T_ + q0 + wid * 16 + l15) * E_ + h * 64;
#pragma unroll
    for (int dt = 0; dt < 4; dt++)
#pragma unroll
        for (int r = 0; r < 4; r++)
            y[yrow + dt * 16 + quad * 4 + r] = f2bf(o[dt][r] * rl);
}

// ---------------------------------------------------------------------------
extern "C" void kernel_launch(void* const* d_in, const int* in_sizes, int n_in,
                              void* d_out, int out_size, void* d_ws, size_t ws_size,
                              hipStream_t stream) {
    const float* x_in  = (const float*)d_in[0];
    const float* Wqkv  = (const float*)d_in[1];
    const float* bqkv  = (const float*)d_in[2];
    const float* Wproj = (const float*)d_in[3];
    const float* bproj = (const float*)d_in[4];
    const float* W1    = (const float*)d_in[5];
    const float* b1    = (const float*)d_in[6];
    const float* W2    = (const float*)d_in[7];
    const float* b2    = (const float*)d_in[8];
    float* out = (float*)d_out;

    // workspace layout (bf16 elements): ~96 MB total
    u16* WT   = (u16*)d_ws;            // 12,582,912  per-layer transposed weights
    u16* qkvb = WT   + 12582912;       // 12,582,912  [4096][3072]
    u16* yb   = qkvb + 12582912;       //  4,194,304  [4096][1024]
    u16* hb   = yb   + 4194304;        // 16,777,216  [4096][4096]
    u16* xb   = hb   + 16777216;       //  4,194,304  [4096][1024]

    for (int l = 0; l < L_; l++) {
        transpose_weights<<<12288, 256, 0, stream>>>(
            Wqkv + (size_t)l * E_ * 3 * E_, Wproj + (size_t)l * E_ * E_,
            W1 + (size_t)l * E_ * FF_, W2 + (size_t)l * FF_ * E_, WT);

        const float* xcur = (l == 0) ? x_in : out;
        convert_kernel<<<4096, 256, 0, stream>>>(xcur, xb, M_ * E_ / 4);

        // qkv = x @ Wqkv + bqkv            -> bf16 [4096][3072]
        gemm_kernel<0><<<dim3(24, 32), 256, 0, stream>>>(
            xb, WT, bqkv + l * 3 * E_, nullptr, qkvb, M_, 3 * E_, E_);

        attn_kernel<<<dim3(T_ / 64, H_, B_), 256, 0, stream>>>(qkvb, yb);

        // x = x + y @ Wproj + bproj        -> f32 d_out
        gemm_kernel<1><<<dim3(8, 32), 256, 0, stream>>>(
            yb, WT + 3145728, bproj + l * E_, xcur, out, M_, E_, E_);

        convert_kernel<<<4096, 256, 0, stream>>>(out, xb, M_ * E_ / 4);

        // h = gelu(x @ W1 + b1)            -> bf16 [4096][4096]
        gemm_kernel<2><<<dim3(32, 32), 256, 0, stream>>>(
            xb, WT + 4194304, b1 + l * FF_, nullptr, hb, M_, FF_, E_);

        // x = x + h @ W2 + b2              -> f32 d_out
        gemm_kernel<1><<<dim3(8, 32), 256, 0, stream>>>(
            hb, WT + 8388608, b2 + l * E_, out, out, M_, E_, FF_);
    }
}

// Round 2
// 1534.884 us; speedup vs baseline: 1.0650x; 1.0650x over previous
//
#include <hip/hip_runtime.h>
#include <hip/hip_bf16.h>

#define B_  2
#define T_  2048
#define E_  1024
#define H_  16
#define HD_ 64
#define FF_ 4096
#define L_  4
#define M_  (B_*T_)   // 4096 tokens

typedef unsigned short u16;
typedef __attribute__((ext_vector_type(8))) short  short8;  // 8 bf16 (4 VGPRs)
typedef __attribute__((ext_vector_type(4))) float  f32x4;   // MFMA C/D frag

// softmax scale folded into q: (1/sqrt(64)) * log2(e)
#define QS 0.18033688011112042f

__device__ __forceinline__ u16 f2bf(float f) {              // RNE
    union { float f; unsigned u; } v; v.f = f;
    unsigned r = (v.u + 0x7fffu + ((v.u >> 16) & 1u)) >> 16;
    return (u16)r;
}
__device__ __forceinline__ u16 f2bf_trunc(float f) {        // cheap, for P only
    union { float f; unsigned u; } v; v.f = f;
    return (u16)(v.u >> 16);
}

// async global->LDS, 16B per lane; LDS dest is wave-uniform base + lane*16
__device__ __forceinline__ void gll16(const u16* g, u16* lds) {
    __builtin_amdgcn_global_load_lds(
        (const __attribute__((address_space(1))) unsigned int*)g,
        (__attribute__((address_space(3))) unsigned int*)lds, 16, 0, 0);
}

// ---------------------------------------------------------------------------
// Weight transpose + fp32->bf16: WT[n][k] = bf16(W[k][n]); one launch per layer
// ---------------------------------------------------------------------------
__global__ __launch_bounds__(256) void transpose_weights(
    const float* __restrict__ Wqkv, const float* __restrict__ Wproj,
    const float* __restrict__ W1,   const float* __restrict__ W2,
    u16* __restrict__ WT) {
    __shared__ float tile[32][33];
    int bid = blockIdx.x;
    const float* src; u16* dst; int K, N, lt;
    if (bid < 3072)      { src = Wqkv;  dst = WT;           K = 1024; N = 3072; lt = bid;        }
    else if (bid < 4096) { src = Wproj; dst = WT + 3145728; K = 1024; N = 1024; lt = bid - 3072; }
    else if (bid < 8192) { src = W1;    dst = WT + 4194304; K = 1024; N = 4096; lt = bid - 4096; }
    else                 { src = W2;    dst = WT + 8388608; K = 4096; N = 1024; lt = bid - 8192; }
    int tpr = N >> 5;
    int ti = lt / tpr, tj = lt % tpr;
    int k0 = ti << 5, n0 = tj << 5;
    int tx = threadIdx.x & 31, ty = threadIdx.x >> 5;
    for (int i = 0; i < 4; i++) {
        int r = ty + (i << 3);
        tile[r][tx] = src[(size_t)(k0 + r) * N + n0 + tx];
    }
    __syncthreads();
    for (int i = 0; i < 4; i++) {
        int r = ty + (i << 3);
        dst[(size_t)(n0 + r) * K + k0 + tx] = f2bf(tile[tx][r]);
    }
}

// ---------------------------------------------------------------------------
__global__ __launch_bounds__(256) void convert_kernel(
    const float* __restrict__ in, u16* __restrict__ out, int n4) {
    int i = blockIdx.x * 256 + threadIdx.x;
    if (i < n4) {
        float4 v = ((const float4*)in)[i];
        ushort4 w;
        w.x = f2bf(v.x); w.y = f2bf(v.y); w.z = f2bf(v.z); w.w = f2bf(v.w);
        ((ushort4*)out)[i] = w;
    }
}

// ---------------------------------------------------------------------------
// m97-structure MFMA GEMM: C[M][N] = A[M][K](bf16) * WT[N][K]^T(bf16) + bias
// EPI 0: out bf16 = C              (cols < E_ scaled by QS — qkv only)
// EPI 1: out f32  = C + res;  out2 bf16 = same  (fused residual + convert)
// EPI 2: out bf16 = gelu_tanh(C)
// 128x128 tile, BK=32, 4 waves (2x2), 4x4 16x16x32 mfma per wave.
// LDS rows: 32 u16 = 64 B, UNPADDED (global_load_lds lane-contiguity, m104);
// b128 frag reads are bank-balanced at the 8-cyc b128 floor.
// ---------------------------------------------------------------------------
template <int EPI>
__global__ __launch_bounds__(256) void gemm_kernel(
    const u16* __restrict__ A, const u16* __restrict__ Bt,
    const float* __restrict__ bias, const float* __restrict__ res,
    void* outp, u16* __restrict__ out2, int M, int N, int K) {
    __shared__ u16 As[128 * 32];
    __shared__ u16 Bs[128 * 32];
    int t = threadIdx.x;
    int wid = t >> 6, lane = t & 63;
    int m0 = blockIdx.y << 7, n0 = blockIdx.x << 7;
    int l15 = t & 15, quad = (t >> 4) & 3;
    int wr = wid >> 1, wc = wid & 1;
    f32x4 acc[4][4];
#pragma unroll
    for (int i = 0; i < 4; i++)
#pragma unroll
        for (int j = 0; j < 4; j++) acc[i][j] = (f32x4){0.f, 0.f, 0.f, 0.f};

    // staging: wave wid owns rows [wid*32, wid*32+32); 2 wave-loads each matrix
    int srow = (wid << 5) + (lane >> 2);       // row this lane's 16B belongs to
    int kch  = (lane & 3) << 3;                // k-offset (8 u16)
    const u16* gA = &A [(size_t)(m0 + srow) * K + kch];
    const u16* gB = &Bt[(size_t)(n0 + srow) * K + kch];

    for (int k0 = 0; k0 < K; k0 += 32) {
        __syncthreads();
#pragma unroll
        for (int j = 0; j < 2; j++) {
            gll16(gA + (size_t)(j << 4) * K + k0, &As[((wid << 5) + (j << 4)) << 5]);
            gll16(gB + (size_t)(j << 4) * K + k0, &Bs[((wid << 5) + (j << 4)) << 5]);
        }
        __syncthreads();   // drains vmcnt(0): LDS tiles ready
        short8 af[4], bf[4];
#pragma unroll
        for (int i = 0; i < 4; i++)
            af[i] = *(const short8*)&As[((wr << 6) + (i << 4) + l15) * 32 + (quad << 3)];
#pragma unroll
        for (int j = 0; j < 4; j++)
            bf[j] = *(const short8*)&Bs[((wc << 6) + (j << 4) + l15) * 32 + (quad << 3)];
#pragma unroll
        for (int i = 0; i < 4; i++)
#pragma unroll
            for (int j = 0; j < 4; j++)
                acc[i][j] = __builtin_amdgcn_mfma_f32_16x16x32_bf16(af[i], bf[j], acc[i][j], 0, 0, 0);
    }
    // epilogue: C/D layout col = lane&15, row = quad*4 + reg  [m89/m91]
#pragma unroll
    for (int j = 0; j < 4; j++) {
        int gn = (n0 + (wc << 6) + (j << 4)) + l15;
        float bv = bias[gn];
#pragma unroll
        for (int i = 0; i < 4; i++) {
            int mb = m0 + (wr << 6) + (i << 4) + (quad << 2);
#pragma unroll
            for (int r = 0; r < 4; r++) {
                size_t idx = (size_t)(mb + r) * N + gn;
                float v = acc[i][j][r] + bv;
                if (EPI == 0) {
                    if (gn < E_) v *= QS;            // fold softmax scale into q
                    ((u16*)outp)[idx] = f2bf(v);
                } else if (EPI == 1) {
                    float o = v + res[idx];
                    ((float*)outp)[idx] = o;
                    out2[idx] = f2bf(o);
                } else {
                    float u  = 0.7978845608028654f * (v + 0.044715f * v * v * v);
                    float th = 1.f - 2.f / (__expf(2.f * u) + 1.f);
                    ((u16*)outp)[idx] = f2bf(0.5f * v * (1.f + th));
                }
            }
        }
    }
}

// ---------------------------------------------------------------------------
// MFMA flash attention, KC=64 keys/chunk. Block = (b, h, 64 q-rows), 4 waves.
// S^T = K.Q^T (both natural layout); q pre-scaled by QS at qkv-GEMM epilogue,
// softmax in exp2 domain. O^T = V^T.P^T; V transposed at staging with packed
// b32 writes (2-way = free, m136); P round-trips LDS (C-layout -> B-frag).
// ---------------------------------------------------------------------------
__global__ __launch_bounds__(256) void attn_kernel(
    const u16* __restrict__ qkv, u16* __restrict__ y) {
    __shared__ u16 Qs[64 * 72];
    __shared__ u16 Ks[64 * 72];
    __shared__ u16 Vt[64 * 72];       // [d][key], 64 keys + pad
    __shared__ u16 Pb[4 * 16 * 72];   // per-wave [q][key]

    int t = threadIdx.x;
    int q0 = blockIdx.x << 6;
    int h  = blockIdx.y;
    int b  = blockIdx.z;
    const size_t rs = 3 * E_;
    const u16* base = qkv + (size_t)b * T_ * rs;

    {   // stage Q (64 x 64)
        int r8 = t >> 3, dch = (t & 7) << 3;
#pragma unroll
        for (int p = 0; p < 2; p++) {
            int r = r8 + (p << 5);
            *(uint4*)&Qs[r * 72 + dch] =
                *(const uint4*)&base[(size_t)(q0 + r) * rs + h * 64 + dch];
        }
    }
    __syncthreads();
    int wid = t >> 6, l15 = t & 15, quad = (t >> 4) & 3;
    short8 qf0 = *(const short8*)&Qs[(wid * 16 + l15) * 72 + quad * 8];
    short8 qf1 = *(const short8*)&Qs[(wid * 16 + l15) * 72 + 32 + quad * 8];

    float m = -1e30f, l = 0.f;
    f32x4 o[4];
#pragma unroll
    for (int dt = 0; dt < 4; dt++) o[dt] = (f32x4){0.f, 0.f, 0.f, 0.f};

    int kkey = t >> 3, kch = (t & 7) << 3;   // K staging map
    int vkp = t & 31, vdc = t >> 5;          // V staging: 2 keys, 8 d's per lane

    for (int c0 = 0; c0 < T_; c0 += 64) {
#pragma unroll
        for (int p = 0; p < 2; p++) {
            int key = kkey + (p << 5);
            *(uint4*)&Ks[key * 72 + kch] =
                *(const uint4*)&base[(size_t)(c0 + key) * rs + E_ + h * 64 + kch];
        }
        {   // V transpose: packed b32 writes (keys 2vkp, 2vkp+1)
            union { uint4 v; u16 u[8]; } v0, v1;
            v0.v = *(const uint4*)&base[(size_t)(c0 + 2 * vkp) * rs + 2 * E_ + h * 64 + (vdc << 3)];
            v1.v = *(const uint4*)&base[(size_t)(c0 + 2 * vkp + 1) * rs + 2 * E_ + h * 64 + (vdc << 3)];
#pragma unroll
            for (int i = 0; i < 8; i++) {
                unsigned pk = (unsigned)v0.u[i] | ((unsigned)v1.u[i] << 16);
                *(unsigned*)&Vt[(vdc * 8 + i) * 72 + 2 * vkp] = pk;
            }
        }
        __syncthreads();

        f32x4 s[4];
#pragma unroll
        for (int kt = 0; kt < 4; kt++) {
            short8 ka0 = *(const short8*)&Ks[(kt * 16 + l15) * 72 + quad * 8];
            short8 ka1 = *(const short8*)&Ks[(kt * 16 + l15) * 72 + 32 + quad * 8];
            f32x4 z = (f32x4){0.f, 0.f, 0.f, 0.f};
            z = __builtin_amdgcn_mfma_f32_16x16x32_bf16(ka0, qf0, z, 0, 0, 0);
            z = __builtin_amdgcn_mfma_f32_16x16x32_bf16(ka1, qf1, z, 0, 0, 0);
            s[kt] = z;
        }
        float cm = -1e30f;
#pragma unroll
        for (int kt = 0; kt < 4; kt++)
#pragma unroll
            for (int r = 0; r < 4; r++) cm = fmaxf(cm, s[kt][r]);
        cm = fmaxf(cm, __shfl_xor(cm, 16));
        cm = fmaxf(cm, __shfl_xor(cm, 32));
        float mn = fmaxf(m, cm);
        float alpha = exp2f(m - mn);
        float rsum = 0.f;
        float p[4][4];
#pragma unroll
        for (int kt = 0; kt < 4; kt++)
#pragma unroll
            for (int r = 0; r < 4; r++) {
                p[kt][r] = exp2f(s[kt][r] - mn);
                rsum += p[kt][r];
            }
        rsum += __shfl_xor(rsum, 16);
        rsum += __shfl_xor(rsum, 32);
        l = l * alpha + rsum;
        m = mn;
#pragma unroll
        for (int dt = 0; dt < 4; dt++)
#pragma unroll
            for (int r = 0; r < 4; r++) o[dt][r] *= alpha;

        // P^T (C-layout) -> Pb[q][key]
#pragma unroll
        for (int kt = 0; kt < 4; kt++) {
            ushort4 w;
            w.x = f2bf_trunc(p[kt][0]); w.y = f2bf_trunc(p[kt][1]);
            w.z = f2bf_trunc(p[kt][2]); w.w = f2bf_trunc(p[kt][3]);
            *(ushort4*)&Pb[(wid * 16 + l15) * 72 + kt * 16 + quad * 4] = w;
        }
        __threadfence_block();

        short8 pb0 = *(const short8*)&Pb[(wid * 16 + l15) * 72 + quad * 8];
        short8 pb1 = *(const short8*)&Pb[(wid * 16 + l15) * 72 + 32 + quad * 8];
#pragma unroll
        for (int dt = 0; dt < 4; dt++) {
            short8 vf0 = *(const short8*)&Vt[(dt * 16 + l15) * 72 + quad * 8];
            short8 vf1 = *(const short8*)&Vt[(dt * 16 + l15) * 72 + 32 + quad * 8];
            o[dt] = __builtin_amdgcn_mfma_f32_16x16x32_bf16(vf0, pb0, o[dt], 0, 0, 0);
            o[dt] = __builtin_amdgcn_mfma_f32_16x16x32_bf16(vf1, pb1, o[dt], 0, 0, 0);
        }
        __syncthreads();
    }
    float rl = 1.f / l;
    size_t yrow = ((size_t)b * T_ + q0 + wid * 16 + l15) * E_ + h * 64;
#pragma unroll
    for (int dt = 0; dt < 4; dt++) {
        ushort4 w;
        w.x = f2bf(o[dt][0] * rl); w.y = f2bf(o[dt][1] * rl);
        w.z = f2bf(o[dt][2] * rl); w.w = f2bf(o[dt][3] * rl);
        *(ushort4*)&y[yrow + dt * 16 + quad * 4] = w;
    }
}

// ---------------------------------------------------------------------------
extern "C" void kernel_launch(void* const* d_in, const int* in_sizes, int n_in,
                              void* d_out, int out_size, void* d_ws, size_t ws_size,
                              hipStream_t stream) {
    const float* x_in  = (const float*)d_in[0];
    const float* Wqkv  = (const float*)d_in[1];
    const float* bqkv  = (const float*)d_in[2];
    const float* Wproj = (const float*)d_in[3];
    const float* bproj = (const float*)d_in[4];
    const float* W1    = (const float*)d_in[5];
    const float* b1    = (const float*)d_in[6];
    const float* W2    = (const float*)d_in[7];
    const float* b2    = (const float*)d_in[8];
    float* out = (float*)d_out;

    // workspace (bf16 elements), ~101 MB
    u16* WT   = (u16*)d_ws;            // 12,582,912
    u16* qkvb = WT   + 12582912;       // 12,582,912
    u16* yb   = qkvb + 12582912;       //  4,194,304
    u16* hb   = yb   + 4194304;        // 16,777,216
    u16* xb   = hb   + 16777216;       //  4,194,304

    convert_kernel<<<4096, 256, 0, stream>>>(x_in, xb, M_ * E_ / 4);

    for (int l = 0; l < L_; l++) {
        transpose_weights<<<12288, 256, 0, stream>>>(
            Wqkv + (size_t)l * E_ * 3 * E_, Wproj + (size_t)l * E_ * E_,
            W1 + (size_t)l * E_ * FF_, W2 + (size_t)l * FF_ * E_, WT);

        const float* xcur = (l == 0) ? x_in : out;

        // qkv = x @ Wqkv + bqkv (q cols pre-scaled by QS) -> bf16
        gemm_kernel<0><<<dim3(24, 32), 256, 0, stream>>>(
            xb, WT, bqkv + l * 3 * E_, nullptr, qkvb, nullptr, M_, 3 * E_, E_);

        attn_kernel<<<dim3(T_ / 64, H_, B_), 256, 0, stream>>>(qkvb, yb);

        // x = x + y @ Wproj + bproj -> f32 out, bf16 xb
        gemm_kernel<1><<<dim3(8, 32), 256, 0, stream>>>(
            yb, WT + 3145728, bproj + l * E_, xcur, out, xb, M_, E_, E_);

        // h = gelu(x @ W1 + b1) -> bf16
        gemm_kernel<2><<<dim3(32, 32), 256, 0, stream>>>(
            xb, WT + 4194304, b1 + l * FF_, nullptr, hb, nullptr, M_, FF_, E_);

        // x = x + h @ W2 + b2 -> f32 out, bf16 xb (next layer's input)
        gemm_kernel<1><<<dim3(8, 32), 256, 0, stream>>>(
            hb, WT + 8388608, b2 + l * E_, out, out, xb, M_, E_, FF_);
    }
}

// Round 3
// 1344.897 us; speedup vs baseline: 1.2154x; 1.1413x over previous
//
#include <hip/hip_runtime.h>
#include <hip/hip_bf16.h>

#define B_  2
#define T_  2048
#define E_  1024
#define H_  16
#define HD_ 64
#define FF_ 4096
#define L_  4
#define M_  (B_*T_)   // 4096 tokens

typedef unsigned short u16;
typedef __attribute__((ext_vector_type(8))) short  short8;  // 8 bf16 (4 VGPRs)
typedef __attribute__((ext_vector_type(4))) float  f32x4;   // MFMA C/D frag

// softmax scale folded into q: (1/sqrt(64)) * log2(e)
#define QS 0.18033688011112042f

__device__ __forceinline__ u16 f2bf(float f) {              // RNE
    union { float f; unsigned u; } v; v.f = f;
    unsigned r = (v.u + 0x7fffu + ((v.u >> 16) & 1u)) >> 16;
    return (u16)r;
}
__device__ __forceinline__ u16 f2bf_trunc(float f) {        // cheap, for P only
    union { float f; unsigned u; } v; v.f = f;
    return (u16)(v.u >> 16);
}

// async global->LDS, 16B per lane; LDS dest is wave-uniform base + lane*16
__device__ __forceinline__ void gll16(const u16* g, u16* lds) {
    __builtin_amdgcn_global_load_lds(
        (const __attribute__((address_space(1))) unsigned int*)g,
        (__attribute__((address_space(3))) unsigned int*)lds, 16, 0, 0);
}

// ---------------------------------------------------------------------------
// Weight transpose + fp32->bf16: WT[n][k] = bf16(W[k][n]); one launch per layer
// ---------------------------------------------------------------------------
__global__ __launch_bounds__(256) void transpose_weights(
    const float* __restrict__ Wqkv, const float* __restrict__ Wproj,
    const float* __restrict__ W1,   const float* __restrict__ W2,
    u16* __restrict__ WT) {
    __shared__ float tile[32][33];
    int bid = blockIdx.x;
    const float* src; u16* dst; int K, N, lt;
    if (bid < 3072)      { src = Wqkv;  dst = WT;           K = 1024; N = 3072; lt = bid;        }
    else if (bid < 4096) { src = Wproj; dst = WT + 3145728; K = 1024; N = 1024; lt = bid - 3072; }
    else if (bid < 8192) { src = W1;    dst = WT + 4194304; K = 1024; N = 4096; lt = bid - 4096; }
    else                 { src = W2;    dst = WT + 8388608; K = 4096; N = 1024; lt = bid - 8192; }
    int tpr = N >> 5;
    int ti = lt / tpr, tj = lt % tpr;
    int k0 = ti << 5, n0 = tj << 5;
    int tx = threadIdx.x & 31, ty = threadIdx.x >> 5;
    for (int i = 0; i < 4; i++) {
        int r = ty + (i << 3);
        tile[r][tx] = src[(size_t)(k0 + r) * N + n0 + tx];
    }
    __syncthreads();
    for (int i = 0; i < 4; i++) {
        int r = ty + (i << 3);
        dst[(size_t)(n0 + r) * K + k0 + tx] = f2bf(tile[tx][r]);
    }
}

// ---------------------------------------------------------------------------
__global__ __launch_bounds__(256) void convert_kernel(
    const float* __restrict__ in, u16* __restrict__ out, int n4) {
    int i = blockIdx.x * 256 + threadIdx.x;
    if (i < n4) {
        float4 v = ((const float4*)in)[i];
        ushort4 w;
        w.x = f2bf(v.x); w.y = f2bf(v.y); w.z = f2bf(v.z); w.w = f2bf(v.w);
        ((ushort4*)out)[i] = w;
    }
}

// ---------------------------------------------------------------------------
// m97-structure MFMA GEMM (large-N shapes: qkv, mlp1).
// C[M][N] = A[M][K](bf16) * WT[N][K]^T(bf16) + bias
// EPI 0: out bf16 = C (cols < E_ scaled by QS — qkv only)
// EPI 2: out bf16 = gelu_tanh(C)
// 128x128 tile, BK=32, 4 waves (2x2), 4x4 16x16x32 mfma per wave.
// LDS rows 32 u16 (64 B), XOR-swizzled 16B k-chunks: chunk' = chunk ^
// ((row>>1)&3), applied at the per-lane GLOBAL fetch address (gll LDS layout
// is lane-ordered, m104) and compensated at frag reads -> bank-uniform
// b128 reads (8 lanes per 4-bank group = the 1KB/128B floor).
// ---------------------------------------------------------------------------
template <int EPI>
__global__ __launch_bounds__(256) void gemm_kernel(
    const u16* __restrict__ A, const u16* __restrict__ Bt,
    const float* __restrict__ bias, void* outp, int M, int N, int K) {
    __shared__ u16 As[128 * 32];
    __shared__ u16 Bs[128 * 32];
    int t = threadIdx.x;
    int wid = t >> 6, lane = t & 63;
    int m0 = blockIdx.y << 7, n0 = blockIdx.x << 7;
    int l15 = t & 15, quad = (t >> 4) & 3;
    int wr = wid >> 1, wc = wid & 1;
    f32x4 acc[4][4];
#pragma unroll
    for (int i = 0; i < 4; i++)
#pragma unroll
        for (int j = 0; j < 4; j++) acc[i][j] = (f32x4){0.f, 0.f, 0.f, 0.f};

    int srow = (wid << 5) + (lane >> 2);                 // staged row
    int kch  = (((lane & 3) ^ ((lane >> 3) & 3)) << 3);  // swizzled k-chunk
    const u16* gA = &A [(size_t)(m0 + srow) * K + kch];
    const u16* gB = &Bt[(size_t)(n0 + srow) * K + kch];
    int xo = (l15 >> 1) & 3;                             // frag-read xor

    for (int k0 = 0; k0 < K; k0 += 32) {
        __syncthreads();
#pragma unroll
        for (int j = 0; j < 2; j++) {
            gll16(gA + (size_t)(j << 4) * K + k0, &As[((wid << 5) + (j << 4)) << 5]);
            gll16(gB + (size_t)(j << 4) * K + k0, &Bs[((wid << 5) + (j << 4)) << 5]);
        }
        __syncthreads();   // vmcnt(0): tiles ready
        short8 af[4], bf[4];
#pragma unroll
        for (int i = 0; i < 4; i++)
            af[i] = *(const short8*)&As[((wr << 6) + (i << 4) + l15) * 32 + ((quad ^ xo) << 3)];
#pragma unroll
        for (int j = 0; j < 4; j++)
            bf[j] = *(const short8*)&Bs[((wc << 6) + (j << 4) + l15) * 32 + ((quad ^ xo) << 3)];
#pragma unroll
        for (int i = 0; i < 4; i++)
#pragma unroll
            for (int j = 0; j < 4; j++)
                acc[i][j] = __builtin_amdgcn_mfma_f32_16x16x32_bf16(af[i], bf[j], acc[i][j], 0, 0, 0);
    }
    // epilogue: C/D layout col = lane&15, row = quad*4 + reg  [m89/m91]
#pragma unroll
    for (int j = 0; j < 4; j++) {
        int gn = (n0 + (wc << 6) + (j << 4)) + l15;
        float bv = bias[gn];
#pragma unroll
        for (int i = 0; i < 4; i++) {
            int mb = m0 + (wr << 6) + (i << 4) + (quad << 2);
#pragma unroll
            for (int r = 0; r < 4; r++) {
                size_t idx = (size_t)(mb + r) * N + gn;
                float v = acc[i][j][r] + bv;
                if (EPI == 0) {
                    if (gn < E_) v *= QS;            // fold softmax scale into q
                    ((u16*)outp)[idx] = f2bf(v);
                } else {
                    float u  = 0.7978845608028654f * (v + 0.044715f * v * v * v);
                    float th = 1.f - 2.f / (__expf(2.f * u) + 1.f);
                    ((u16*)outp)[idx] = f2bf(0.5f * v * (1.f + th));
                }
            }
        }
    }
}

// ---------------------------------------------------------------------------
// N=1024 GEMM (proj, mlp2): 128x64 tile, BK=64, DOUBLE-BUFFERED single-barrier
// K-loop. Grid 16x32 = 512 blocks = 2 blocks/CU (vs 256 = 1/CU at 128x128,
// which serialized every k-iter behind the vmcnt(0) barrier drain).
// Prefetch gll(k+1) issues right after the barrier -> drained one full
// iteration later at the next barrier. 48 KB LDS. Same XOR swizzle (8-chunk
// rows: chunk' = chunk ^ (row&7)).
// out f32 = C + bias + res; out2 bf16 mirror (fused residual + convert).
// ---------------------------------------------------------------------------
__global__ __launch_bounds__(256) void gemm_n64(
    const u16* __restrict__ A, const u16* __restrict__ Bt,
    const float* __restrict__ bias, const float* __restrict__ res,
    float* __restrict__ outp, u16* __restrict__ out2, int M, int N, int K) {
    __shared__ u16 As[2][128 * 64];   // 16 KB each
    __shared__ u16 Bs[2][64 * 64];    //  8 KB each
    int t = threadIdx.x;
    int wid = t >> 6, lane = t & 63;
    int m0 = blockIdx.y << 7, n0 = blockIdx.x << 6;
    int l15 = t & 15, quad = (t >> 4) & 3;
    int wr = wid >> 1, wc = wid & 1;   // wave tile: 64(m) x 32(n)
    f32x4 acc[4][2];
#pragma unroll
    for (int i = 0; i < 4; i++)
#pragma unroll
        for (int j = 0; j < 2; j++) acc[i][j] = (f32x4){0.f, 0.f, 0.f, 0.f};

    int srow = lane >> 3;                          // row within 8-row group
    int kch  = (((lane & 7) ^ srow) << 3);         // swizzled k-chunk (u16)
    const u16* gA = &A [(size_t)(m0 + (wid << 5) + srow) * K + kch];
    const u16* gB = &Bt[(size_t)(n0 + (wid << 4) + srow) * K + kch];
    int xo = l15 & 7;

    int nk = K >> 6;
    // prologue: stage tile 0 into buffer 0
#pragma unroll
    for (int g = 0; g < 4; g++)
        gll16(gA + (size_t)(g << 3) * K, &As[0][((wid << 5) + (g << 3)) << 6]);
#pragma unroll
    for (int g = 0; g < 2; g++)
        gll16(gB + (size_t)(g << 3) * K, &Bs[0][((wid << 4) + (g << 3)) << 6]);

    for (int kk = 0; kk < nk; kk++) {
        __syncthreads();                // drains gll(kk) (issued 1 iter ago)
        int b = kk & 1;
        if (kk + 1 < nk) {              // prefetch tile kk+1 into other buffer
            int k1 = (kk + 1) << 6;
#pragma unroll
            for (int g = 0; g < 4; g++)
                gll16(gA + (size_t)(g << 3) * K + k1, &As[b ^ 1][((wid << 5) + (g << 3)) << 6]);
#pragma unroll
            for (int g = 0; g < 2; g++)
                gll16(gB + (size_t)(g << 3) * K + k1, &Bs[b ^ 1][((wid << 4) + (g << 3)) << 6]);
        }
        short8 af[2][4], bf[2][2];
#pragma unroll
        for (int kq = 0; kq < 2; kq++) {
            int ch = (((kq << 2) | quad) ^ xo) << 3;
#pragma unroll
            for (int i = 0; i < 4; i++)
                af[kq][i] = *(const short8*)&As[b][((wr << 6) + (i << 4) + l15) * 64 + ch];
#pragma unroll
            for (int j = 0; j < 2; j++)
                bf[kq][j] = *(const short8*)&Bs[b][((wc << 5) + (j << 4) + l15) * 64 + ch];
        }
#pragma unroll
        for (int kq = 0; kq < 2; kq++)
#pragma unroll
            for (int i = 0; i < 4; i++)
#pragma unroll
                for (int j = 0; j < 2; j++)
                    acc[i][j] = __builtin_amdgcn_mfma_f32_16x16x32_bf16(
                        af[kq][i], bf[kq][j], acc[i][j], 0, 0, 0);
    }
#pragma unroll
    for (int j = 0; j < 2; j++) {
        int gn = n0 + (wc << 5) + (j << 4) + l15;
        float bv = bias[gn];
#pragma unroll
        for (int i = 0; i < 4; i++) {
            int mb = m0 + (wr << 6) + (i << 4) + (quad << 2);
#pragma unroll
            for (int r = 0; r < 4; r++) {
                size_t idx = (size_t)(mb + r) * N + gn;
                float o = acc[i][j][r] + bv + res[idx];
                outp[idx] = o;
                out2[idx] = f2bf(o);
            }
        }
    }
}

// ---------------------------------------------------------------------------
// MFMA flash attention, KC=64 keys/chunk. Block = (b, h, 64 q-rows), 4 waves.
// ---------------------------------------------------------------------------
__global__ __launch_bounds__(256) void attn_kernel(
    const u16* __restrict__ qkv, u16* __restrict__ y) {
    __shared__ u16 Qs[64 * 72];
    __shared__ u16 Ks[64 * 72];
    __shared__ u16 Vt[64 * 72];       // [d][key]
    __shared__ u16 Pb[4 * 16 * 72];   // per-wave [q][key]

    int t = threadIdx.x;
    int q0 = blockIdx.x << 6;
    int h  = blockIdx.y;
    int b  = blockIdx.z;
    const size_t rs = 3 * E_;
    const u16* base = qkv + (size_t)b * T_ * rs;

    {   // stage Q (64 x 64)
        int r8 = t >> 3, dch = (t & 7) << 3;
#pragma unroll
        for (int p = 0; p < 2; p++) {
            int r = r8 + (p << 5);
            *(uint4*)&Qs[r * 72 + dch] =
                *(const uint4*)&base[(size_t)(q0 + r) * rs + h * 64 + dch];
        }
    }
    __syncthreads();
    int wid = t >> 6, l15 = t & 15, quad = (t >> 4) & 3;
    short8 qf0 = *(const short8*)&Qs[(wid * 16 + l15) * 72 + quad * 8];
    short8 qf1 = *(const short8*)&Qs[(wid * 16 + l15) * 72 + 32 + quad * 8];

    float m = -1e30f, l = 0.f;
    f32x4 o[4];
#pragma unroll
    for (int dt = 0; dt < 4; dt++) o[dt] = (f32x4){0.f, 0.f, 0.f, 0.f};

    int kkey = t >> 3, kch = (t & 7) << 3;
    int vkp = t & 31, vdc = t >> 5;

    for (int c0 = 0; c0 < T_; c0 += 64) {
#pragma unroll
        for (int p = 0; p < 2; p++) {
            int key = kkey + (p << 5);
            *(uint4*)&Ks[key * 72 + kch] =
                *(const uint4*)&base[(size_t)(c0 + key) * rs + E_ + h * 64 + kch];
        }
        {   // V transpose: packed b32 writes (keys 2vkp, 2vkp+1)
            union { uint4 v; u16 u[8]; } v0, v1;
            v0.v = *(const uint4*)&base[(size_t)(c0 + 2 * vkp) * rs + 2 * E_ + h * 64 + (vdc << 3)];
            v1.v = *(const uint4*)&base[(size_t)(c0 + 2 * vkp + 1) * rs + 2 * E_ + h * 64 + (vdc << 3)];
#pragma unroll
            for (int i = 0; i < 8; i++) {
                unsigned pk = (unsigned)v0.u[i] | ((unsigned)v1.u[i] << 16);
                *(unsigned*)&Vt[(vdc * 8 + i) * 72 + 2 * vkp] = pk;
            }
        }
        __syncthreads();

        f32x4 s[4];
#pragma unroll
        for (int kt = 0; kt < 4; kt++) {
            short8 ka0 = *(const short8*)&Ks[(kt * 16 + l15) * 72 + quad * 8];
            short8 ka1 = *(const short8*)&Ks[(kt * 16 + l15) * 72 + 32 + quad * 8];
            f32x4 z = (f32x4){0.f, 0.f, 0.f, 0.f};
            z = __builtin_amdgcn_mfma_f32_16x16x32_bf16(ka0, qf0, z, 0, 0, 0);
            z = __builtin_amdgcn_mfma_f32_16x16x32_bf16(ka1, qf1, z, 0, 0, 0);
            s[kt] = z;
        }
        float cm = -1e30f;
#pragma unroll
        for (int kt = 0; kt < 4; kt++)
#pragma unroll
            for (int r = 0; r < 4; r++) cm = fmaxf(cm, s[kt][r]);
        cm = fmaxf(cm, __shfl_xor(cm, 16));
        cm = fmaxf(cm, __shfl_xor(cm, 32));
        float mn = fmaxf(m, cm);
        float alpha = exp2f(m - mn);
        float rsum = 0.f;
        float p[4][4];
#pragma unroll
        for (int kt = 0; kt < 4; kt++)
#pragma unroll
            for (int r = 0; r < 4; r++) {
                p[kt][r] = exp2f(s[kt][r] - mn);
                rsum += p[kt][r];
            }
        rsum += __shfl_xor(rsum, 16);
        rsum += __shfl_xor(rsum, 32);
        l = l * alpha + rsum;
        m = mn;
#pragma unroll
        for (int dt = 0; dt < 4; dt++)
#pragma unroll
            for (int r = 0; r < 4; r++) o[dt][r] *= alpha;

#pragma unroll
        for (int kt = 0; kt < 4; kt++) {
            ushort4 w;
            w.x = f2bf_trunc(p[kt][0]); w.y = f2bf_trunc(p[kt][1]);
            w.z = f2bf_trunc(p[kt][2]); w.w = f2bf_trunc(p[kt][3]);
            *(ushort4*)&Pb[(wid * 16 + l15) * 72 + kt * 16 + quad * 4] = w;
        }
        __threadfence_block();

        short8 pb0 = *(const short8*)&Pb[(wid * 16 + l15) * 72 + quad * 8];
        short8 pb1 = *(const short8*)&Pb[(wid * 16 + l15) * 72 + 32 + quad * 8];
#pragma unroll
        for (int dt = 0; dt < 4; dt++) {
            short8 vf0 = *(const short8*)&Vt[(dt * 16 + l15) * 72 + quad * 8];
            short8 vf1 = *(const short8*)&Vt[(dt * 16 + l15) * 72 + 32 + quad * 8];
            o[dt] = __builtin_amdgcn_mfma_f32_16x16x32_bf16(vf0, pb0, o[dt], 0, 0, 0);
            o[dt] = __builtin_amdgcn_mfma_f32_16x16x32_bf16(vf1, pb1, o[dt], 0, 0, 0);
        }
        __syncthreads();
    }
    float rl = 1.f / l;
    size_t yrow = ((size_t)b * T_ + q0 + wid * 16 + l15) * E_ + h * 64;
#pragma unroll
    for (int dt = 0; dt < 4; dt++) {
        ushort4 w;
        w.x = f2bf(o[dt][0] * rl); w.y = f2bf(o[dt][1] * rl);
        w.z = f2bf(o[dt][2] * rl); w.w = f2bf(o[dt][3] * rl);
        *(ushort4*)&y[yrow + dt * 16 + quad * 4] = w;
    }
}

// ---------------------------------------------------------------------------
extern "C" void kernel_launch(void* const* d_in, const int* in_sizes, int n_in,
                              void* d_out, int out_size, void* d_ws, size_t ws_size,
                              hipStream_t stream) {
    const float* x_in  = (const float*)d_in[0];
    const float* Wqkv  = (const float*)d_in[1];
    const float* bqkv  = (const float*)d_in[2];
    const float* Wproj = (const float*)d_in[3];
    const float* bproj = (const float*)d_in[4];
    const float* W1    = (const float*)d_in[5];
    const float* b1    = (const float*)d_in[6];
    const float* W2    = (const float*)d_in[7];
    const float* b2    = (const float*)d_in[8];
    float* out = (float*)d_out;

    // workspace (bf16 elements), ~101 MB
    u16* WT   = (u16*)d_ws;            // 12,582,912
    u16* qkvb = WT   + 12582912;       // 12,582,912
    u16* yb   = qkvb + 12582912;       //  4,194,304
    u16* hb   = yb   + 4194304;        // 16,777,216
    u16* xb   = hb   + 16777216;       //  4,194,304

    convert_kernel<<<4096, 256, 0, stream>>>(x_in, xb, M_ * E_ / 4);

    for (int l = 0; l < L_; l++) {
        transpose_weights<<<12288, 256, 0, stream>>>(
            Wqkv + (size_t)l * E_ * 3 * E_, Wproj + (size_t)l * E_ * E_,
            W1 + (size_t)l * E_ * FF_, W2 + (size_t)l * FF_ * E_, WT);

        const float* xcur = (l == 0) ? x_in : out;

        // qkv = x @ Wqkv + bqkv (q cols pre-scaled by QS) -> bf16
        gemm_kernel<0><<<dim3(24, 32), 256, 0, stream>>>(
            xb, WT, bqkv + l * 3 * E_, qkvb, M_, 3 * E_, E_);

        attn_kernel<<<dim3(T_ / 64, H_, B_), 256, 0, stream>>>(qkvb, yb);

        // x = x + y @ Wproj + bproj -> f32 out, bf16 xb
        gemm_n64<<<dim3(16, 32), 256, 0, stream>>>(
            yb, WT + 3145728, bproj + l * E_, xcur, out, xb, M_, E_, E_);

        // h = gelu(x @ W1 + b1) -> bf16
        gemm_kernel<2><<<dim3(32, 32), 256, 0, stream>>>(
            xb, WT + 4194304, b1 + l * FF_, hb, M_, FF_, E_);

        // x = x + h @ W2 + b2 -> f32 out, bf16 xb (next layer's input)
        gemm_n64<<<dim3(16, 32), 256, 0, stream>>>(
            hb, WT + 8388608, b2 + l * E_, out, out, xb, M_, E_, FF_);
    }
}

// Round 4
// 1196.838 us; speedup vs baseline: 1.3658x; 1.1237x over previous
//
#include <hip/hip_runtime.h>
#include <hip/hip_bf16.h>

#define B_  2
#define T_  2048
#define E_  1024
#define H_  16
#define HD_ 64
#define FF_ 4096
#define L_  4
#define M_  (B_*T_)   // 4096 tokens
#define RS_ (3*E_)    // qkv row stride

typedef unsigned short u16;
typedef __attribute__((ext_vector_type(8))) short  short8;  // 8 bf16 (4 VGPRs)
typedef __attribute__((ext_vector_type(4))) float  f32x4;   // MFMA C/D frag

// softmax scale folded into q: (1/sqrt(64)) * log2(e)
#define QS 0.18033688011112042f

__device__ __forceinline__ u16 f2bf(float f) {              // RNE
    union { float f; unsigned u; } v; v.f = f;
    unsigned r = (v.u + 0x7fffu + ((v.u >> 16) & 1u)) >> 16;
    return (u16)r;
}
__device__ __forceinline__ u16 f2bf_trunc(float f) {        // cheap, for P only
    union { float f; unsigned u; } v; v.f = f;
    return (u16)(v.u >> 16);
}

// async global->LDS, 16B per lane; LDS dest is wave-uniform base + lane*16
__device__ __forceinline__ void gll16(const u16* g, u16* lds) {
    __builtin_amdgcn_global_load_lds(
        (const __attribute__((address_space(1))) unsigned int*)g,
        (__attribute__((address_space(3))) unsigned int*)lds, 16, 0, 0);
}

// ---------------------------------------------------------------------------
// Weight transpose + fp32->bf16: WT[n][k] = bf16(W[k][n]); one launch per layer
// ---------------------------------------------------------------------------
__global__ __launch_bounds__(256) void transpose_weights(
    const float* __restrict__ Wqkv, const float* __restrict__ Wproj,
    const float* __restrict__ W1,   const float* __restrict__ W2,
    u16* __restrict__ WT) {
    __shared__ float tile[32][33];
    int bid = blockIdx.x;
    const float* src; u16* dst; int K, N, lt;
    if (bid < 3072)      { src = Wqkv;  dst = WT;           K = 1024; N = 3072; lt = bid;        }
    else if (bid < 4096) { src = Wproj; dst = WT + 3145728; K = 1024; N = 1024; lt = bid - 3072; }
    else if (bid < 8192) { src = W1;    dst = WT + 4194304; K = 1024; N = 4096; lt = bid - 4096; }
    else                 { src = W2;    dst = WT + 8388608; K = 4096; N = 1024; lt = bid - 8192; }
    int tpr = N >> 5;
    int ti = lt / tpr, tj = lt % tpr;
    int k0 = ti << 5, n0 = tj << 5;
    int tx = threadIdx.x & 31, ty = threadIdx.x >> 5;
    for (int i = 0; i < 4; i++) {
        int r = ty + (i << 3);
        tile[r][tx] = src[(size_t)(k0 + r) * N + n0 + tx];
    }
    __syncthreads();
    for (int i = 0; i < 4; i++) {
        int r = ty + (i << 3);
        dst[(size_t)(n0 + r) * K + k0 + tx] = f2bf(tile[tx][r]);
    }
}

// ---------------------------------------------------------------------------
__global__ __launch_bounds__(256) void convert_kernel(
    const float* __restrict__ in, u16* __restrict__ out, int n4) {
    int i = blockIdx.x * 256 + threadIdx.x;
    if (i < n4) {
        float4 v = ((const float4*)in)[i];
        ushort4 w;
        w.x = f2bf(v.x); w.y = f2bf(v.y); w.z = f2bf(v.z); w.w = f2bf(v.w);
        ((ushort4*)out)[i] = w;
    }
}

// ---------------------------------------------------------------------------
// Double-buffered single-barrier MFMA GEMM (qkv, mlp1).
// C[M][N] = A[M][K](bf16) * WT[N][K]^T(bf16) + bias
// EPI 0: out bf16 = C (cols < E_ scaled by QS — qkv only)
// EPI 2: out bf16 = gelu_tanh(C)
// 128x128 tile, BK=32, prefetch gll(kk+1) issued after barrier kk -> drained
// at barrier kk+1 (gemm_n64-proven pipeline). XOR-swizzled 16B k-chunks.
// ---------------------------------------------------------------------------
template <int EPI>
__global__ __launch_bounds__(256) void gemm_kernel(
    const u16* __restrict__ A, const u16* __restrict__ Bt,
    const float* __restrict__ bias, void* outp, int M, int N, int K) {
    __shared__ u16 As[2][128 * 32];   // 8 KB each
    __shared__ u16 Bs[2][128 * 32];
    int t = threadIdx.x;
    int wid = t >> 6, lane = t & 63;
    int m0 = blockIdx.y << 7, n0 = blockIdx.x << 7;
    int l15 = t & 15, quad = (t >> 4) & 3;
    int wr = wid >> 1, wc = wid & 1;
    f32x4 acc[4][4];
#pragma unroll
    for (int i = 0; i < 4; i++)
#pragma unroll
        for (int j = 0; j < 4; j++) acc[i][j] = (f32x4){0.f, 0.f, 0.f, 0.f};

    int srow = (wid << 5) + (lane >> 2);                 // staged row
    int kch  = (((lane & 3) ^ ((lane >> 3) & 3)) << 3);  // swizzled k-chunk
    const u16* gA = &A [(size_t)(m0 + srow) * K + kch];
    const u16* gB = &Bt[(size_t)(n0 + srow) * K + kch];
    int xo = (l15 >> 1) & 3;                             // frag-read xor
    int abase = (((wr << 6) + l15) << 5) + ((quad ^ xo) << 3);
    int bbase = (((wc << 6) + l15) << 5) + ((quad ^ xo) << 3);

    int nk = K >> 5;
    // prologue: stage tile 0 into buffer 0
#pragma unroll
    for (int g = 0; g < 2; g++) {
        gll16(gA + (size_t)(g << 4) * K, &As[0][((wid << 5) + (g << 4)) << 5]);
        gll16(gB + (size_t)(g << 4) * K, &Bs[0][((wid << 5) + (g << 4)) << 5]);
    }
    for (int kk = 0; kk < nk; kk++) {
        __syncthreads();                // drains gll(kk), frees buf kk^1
        const u16* as = &As[kk & 1][0];
        const u16* bs = &Bs[kk & 1][0];
        if (kk + 1 < nk) {
            int k1 = (kk + 1) << 5;
            int bn = (kk + 1) & 1;
#pragma unroll
            for (int g = 0; g < 2; g++) {
                gll16(gA + (size_t)(g << 4) * K + k1, &As[bn][((wid << 5) + (g << 4)) << 5]);
                gll16(gB + (size_t)(g << 4) * K + k1, &Bs[bn][((wid << 5) + (g << 4)) << 5]);
            }
        }
        short8 af[4], bf[4];
#pragma unroll
        for (int i = 0; i < 4; i++)
            af[i] = *(const short8*)(as + abase + (i << 9));
#pragma unroll
        for (int j = 0; j < 4; j++)
            bf[j] = *(const short8*)(bs + bbase + (j << 9));
#pragma unroll
        for (int i = 0; i < 4; i++)
#pragma unroll
            for (int j = 0; j < 4; j++)
                acc[i][j] = __builtin_amdgcn_mfma_f32_16x16x32_bf16(af[i], bf[j], acc[i][j], 0, 0, 0);
    }
    // epilogue: C/D layout col = lane&15, row = quad*4 + reg  [m89/m91]
#pragma unroll
    for (int j = 0; j < 4; j++) {
        int gn = (n0 + (wc << 6) + (j << 4)) + l15;
        float bv = bias[gn];
#pragma unroll
        for (int i = 0; i < 4; i++) {
            int mb = m0 + (wr << 6) + (i << 4) + (quad << 2);
#pragma unroll
            for (int r = 0; r < 4; r++) {
                size_t idx = (size_t)(mb + r) * N + gn;
                float v = acc[i][j][r] + bv;
                if (EPI == 0) {
                    if (gn < E_) v *= QS;            // fold softmax scale into q
                    ((u16*)outp)[idx] = f2bf(v);
                } else {
                    float u  = 0.7978845608028654f * (v + 0.044715f * v * v * v);
                    float th = 1.f - 2.f / (__expf(2.f * u) + 1.f);
                    ((u16*)outp)[idx] = f2bf(0.5f * v * (1.f + th));
                }
            }
        }
    }
}

// ---------------------------------------------------------------------------
// N=1024 GEMM (proj, mlp2): unchanged from R3 (validated pipeline).
// ---------------------------------------------------------------------------
__global__ __launch_bounds__(256) void gemm_n64(
    const u16* __restrict__ A, const u16* __restrict__ Bt,
    const float* __restrict__ bias, const float* __restrict__ res,
    float* __restrict__ outp, u16* __restrict__ out2, int M, int N, int K) {
    __shared__ u16 As[2][128 * 64];
    __shared__ u16 Bs[2][64 * 64];
    int t = threadIdx.x;
    int wid = t >> 6, lane = t & 63;
    int m0 = blockIdx.y << 7, n0 = blockIdx.x << 6;
    int l15 = t & 15, quad = (t >> 4) & 3;
    int wr = wid >> 1, wc = wid & 1;
    f32x4 acc[4][2];
#pragma unroll
    for (int i = 0; i < 4; i++)
#pragma unroll
        for (int j = 0; j < 2; j++) acc[i][j] = (f32x4){0.f, 0.f, 0.f, 0.f};

    int srow = lane >> 3;
    int kch  = (((lane & 7) ^ srow) << 3);
    const u16* gA = &A [(size_t)(m0 + (wid << 5) + srow) * K + kch];
    const u16* gB = &Bt[(size_t)(n0 + (wid << 4) + srow) * K + kch];
    int xo = l15 & 7;

    int nk = K >> 6;
#pragma unroll
    for (int g = 0; g < 4; g++)
        gll16(gA + (size_t)(g << 3) * K, &As[0][((wid << 5) + (g << 3)) << 6]);
#pragma unroll
    for (int g = 0; g < 2; g++)
        gll16(gB + (size_t)(g << 3) * K, &Bs[0][((wid << 4) + (g << 3)) << 6]);

    for (int kk = 0; kk < nk; kk++) {
        __syncthreads();
        int b = kk & 1;
        if (kk + 1 < nk) {
            int k1 = (kk + 1) << 6;
#pragma unroll
            for (int g = 0; g < 4; g++)
                gll16(gA + (size_t)(g << 3) * K + k1, &As[b ^ 1][((wid << 5) + (g << 3)) << 6]);
#pragma unroll
            for (int g = 0; g < 2; g++)
                gll16(gB + (size_t)(g << 3) * K + k1, &Bs[b ^ 1][((wid << 4) + (g << 3)) << 6]);
        }
        short8 af[2][4], bf[2][2];
#pragma unroll
        for (int kq = 0; kq < 2; kq++) {
            int ch = (((kq << 2) | quad) ^ xo) << 3;
#pragma unroll
            for (int i = 0; i < 4; i++)
                af[kq][i] = *(const short8*)&As[b][((wr << 6) + (i << 4) + l15) * 64 + ch];
#pragma unroll
            for (int j = 0; j < 2; j++)
                bf[kq][j] = *(const short8*)&Bs[b][((wc << 5) + (j << 4) + l15) * 64 + ch];
        }
#pragma unroll
        for (int kq = 0; kq < 2; kq++)
#pragma unroll
            for (int i = 0; i < 4; i++)
#pragma unroll
                for (int j = 0; j < 2; j++)
                    acc[i][j] = __builtin_amdgcn_mfma_f32_16x16x32_bf16(
                        af[kq][i], bf[kq][j], acc[i][j], 0, 0, 0);
    }
#pragma unroll
    for (int j = 0; j < 2; j++) {
        int gn = n0 + (wc << 5) + (j << 4) + l15;
        float bv = bias[gn];
#pragma unroll
        for (int i = 0; i < 4; i++) {
            int mb = m0 + (wr << 6) + (i << 4) + (quad << 2);
#pragma unroll
            for (int r = 0; r < 4; r++) {
                size_t idx = (size_t)(mb + r) * N + gn;
                float o = acc[i][j][r] + bv + res[idx];
                outp[idx] = o;
                out2[idx] = f2bf(o);
            }
        }
    }
}

// ---------------------------------------------------------------------------
// Pipelined MFMA flash attention. KC=64 keys/chunk, double-buffered Ks/Vt,
// ONE barrier per chunk. K staged by gll16 (chunk-XOR swizzle on the global
// fetch address), V prefetched into VGPRs at chunk top and packed->LDS at
// chunk end. All LDS rows stride 64 u16 with phys_chunk = logical ^ (row&7):
// every b128 read = 8 accesses per 4-bank window (conflict-free), 16B-aligned.
// LDS = 16+16+8 = 40 KB exactly -> 4 blocks/CU, grid 1024 fully resident.
// ---------------------------------------------------------------------------
__global__ __launch_bounds__(256) void attn_kernel(
    const u16* __restrict__ qkv, u16* __restrict__ y) {
    __shared__ u16 Ks[2][64 * 64];
    __shared__ u16 Vt[2][64 * 64];
    __shared__ u16 Pb[4][16 * 64];

    int t = threadIdx.x;
    int q0 = blockIdx.x << 6;
    int h  = blockIdx.y;
    int b  = blockIdx.z;
    const u16* bq = qkv + (size_t)b * T_ * RS_;

    int wid = t >> 6, lane = t & 63, l15 = t & 15, quad = (t >> 4) & 3;
    int sw = l15 & 7;
    // shared frag-read offsets (u16): row l15, logical chunk quad / quad+4
    int ro0 = (l15 << 6) + ((quad ^ sw) << 3);
    int ro1 = ro0 ^ 32;
    // K staging (gll16): call g stages rows wid*16+g*8+(lane>>3)
    int krow = (wid << 4) + (lane >> 3);
    size_t kg0 = (size_t)krow * RS_ + E_ + h * 64 + (((lane & 7) ^ (lane >> 3)) << 3);
    // V staging: lane loads keys 2vkp,2vkp+1 at d-chunk vdc
    int vkp = t & 31, vdc = t >> 5;
    size_t vg0 = (size_t)(2 * vkp) * RS_ + 2 * E_ + h * 64 + (vdc << 3);
    // Vt write offsets (b32, swizzled): row d = vdc*8+i
    int vwo[8];
#pragma unroll
    for (int i = 0; i < 8; i++)
        vwo[i] = (((vdc << 3) + i) << 6) + ((((vkp >> 2) ^ i)) << 3) + ((vkp & 3) << 1);
    // Pb write offsets (b64, swizzled): keys kt*16+quad*4..+4 at row l15
    int pwo[4];
#pragma unroll
    for (int kt = 0; kt < 4; kt++)
        pwo[kt] = (l15 << 6) + ((((kt << 1) | (quad >> 1)) ^ sw) << 3) + ((quad & 1) << 2);
    u16* pw = &Pb[wid][0];

    // Q frags straight from global (one-time)
    const u16* qp = bq + (size_t)(q0 + (wid << 4) + l15) * RS_ + h * 64;
    short8 qf0 = *(const short8*)(qp + (quad << 3));
    short8 qf1 = *(const short8*)(qp + (quad << 3) + 32);

    float m = -1e30f, l = 0.f;
    f32x4 o[4];
#pragma unroll
    for (int dt = 0; dt < 4; dt++) o[dt] = (f32x4){0.f, 0.f, 0.f, 0.f};

    // ---- stage chunk 0 ----
    gll16(bq + kg0,            &Ks[0][(wid << 4) << 6]);
    gll16(bq + kg0 + 8 * RS_,  &Ks[0][((wid << 4) + 8) << 6]);
    {
        union { uint4 q; u16 u[8]; } a_, b_;
        a_.q = *(const uint4*)(bq + vg0);
        b_.q = *(const uint4*)(bq + vg0 + RS_);
#pragma unroll
        for (int i = 0; i < 8; i++) {
            unsigned pk = (unsigned)a_.u[i] | ((unsigned)b_.u[i] << 16);
            *(unsigned*)(&Vt[0][0] + vwo[i]) = pk;
        }
    }

#define ATTN_CHUNK(KSB, VTB, KSN, VTN, C0) do {                                \
    __syncthreads();                   /* drain gll(C0); VTB visible */        \
    int cn_ = (C0) + 64;                                                       \
    uint4 v0_, v1_;                                                            \
    bool pf_ = (cn_ < T_);                                                     \
    if (pf_) {                                                                 \
        size_t cb_ = (size_t)cn_ * RS_;                                        \
        gll16(bq + cb_ + kg0,           (KSN) + ((wid << 4) << 6));            \
        gll16(bq + cb_ + kg0 + 8 * RS_, (KSN) + (((wid << 4) + 8) << 6));      \
        v0_ = *(const uint4*)(bq + cb_ + vg0);                                 \
        v1_ = *(const uint4*)(bq + cb_ + vg0 + RS_);                           \
    }                                                                          \
    f32x4 s_[4];                                                               \
    _Pragma("unroll")                                                          \
    for (int kt = 0; kt < 4; kt++) {                                           \
        short8 ka0 = *(const short8*)((KSB) + (kt << 10) + ro0);               \
        short8 ka1 = *(const short8*)((KSB) + (kt << 10) + ro1);               \
        f32x4 z = (f32x4){0.f, 0.f, 0.f, 0.f};                                 \
        z = __builtin_amdgcn_mfma_f32_16x16x32_bf16(ka0, qf0, z, 0, 0, 0);     \
        z = __builtin_amdgcn_mfma_f32_16x16x32_bf16(ka1, qf1, z, 0, 0, 0);     \
        s_[kt] = z;                                                            \
    }                                                                          \
    float cm_ = -1e30f;                                                        \
    _Pragma("unroll")                                                          \
    for (int kt = 0; kt < 4; kt++)                                             \
        _Pragma("unroll")                                                      \
        for (int r = 0; r < 4; r++) cm_ = fmaxf(cm_, s_[kt][r]);               \
    cm_ = fmaxf(cm_, __shfl_xor(cm_, 16));                                     \
    cm_ = fmaxf(cm_, __shfl_xor(cm_, 32));                                     \
    float mn_ = fmaxf(m, cm_);                                                 \
    float alpha_ = __builtin_amdgcn_exp2f(m - mn_);                            \
    float rsum_ = 0.f;                                                         \
    _Pragma("unroll")                                                          \
    for (int kt = 0; kt < 4; kt++) {                                           \
        float p0_ = __builtin_amdgcn_exp2f(s_[kt][0] - mn_);                   \
        float p1_ = __builtin_amdgcn_exp2f(s_[kt][1] - mn_);                   \
        float p2_ = __builtin_amdgcn_exp2f(s_[kt][2] - mn_);                   \
        float p3_ = __builtin_amdgcn_exp2f(s_[kt][3] - mn_);                   \
        rsum_ += (p0_ + p1_) + (p2_ + p3_);                                    \
        ushort4 w_;                                                            \
        w_.x = f2bf_trunc(p0_); w_.y = f2bf_trunc(p1_);                        \
        w_.z = f2bf_trunc(p2_); w_.w = f2bf_trunc(p3_);                        \
        *(ushort4*)(pw + pwo[kt]) = w_;                                        \
    }                                                                          \
    rsum_ += __shfl_xor(rsum_, 16);                                            \
    rsum_ += __shfl_xor(rsum_, 32);                                            \
    l = l * alpha_ + rsum_;                                                    \
    m = mn_;                                                                   \
    __threadfence_block();             /* drain Pb writes (intra-wave) */      \
    short8 pb0 = *(const short8*)(pw + ro0);                                   \
    short8 pb1 = *(const short8*)(pw + ro1);                                   \
    _Pragma("unroll")                                                          \
    for (int dt = 0; dt < 4; dt++) {                                           \
        _Pragma("unroll")                                                      \
        for (int r = 0; r < 4; r++) o[dt][r] *= alpha_;                        \
        short8 vf0 = *(const short8*)((VTB) + (dt << 10) + ro0);               \
        short8 vf1 = *(const short8*)((VTB) + (dt << 10) + ro1);               \
        o[dt] = __builtin_amdgcn_mfma_f32_16x16x32_bf16(vf0, pb0, o[dt], 0, 0, 0); \
        o[dt] = __builtin_amdgcn_mfma_f32_16x16x32_bf16(vf1, pb1, o[dt], 0, 0, 0); \
    }                                                                          \
    if (pf_) {                                                                 \
        union { uint4 q; u16 u[8]; } a_, b_;                                   \
        a_.q = v0_; b_.q = v1_;                                                \
        _Pragma("unroll")                                                      \
        for (int i = 0; i < 8; i++) {                                          \
            unsigned pk_ = (unsigned)a_.u[i] | ((unsigned)b_.u[i] << 16);      \
            *(unsigned*)((VTN) + vwo[i]) = pk_;                                \
        }                                                                      \
    }                                                                          \
} while (0)

    for (int c0 = 0; c0 < T_; c0 += 128) {
        ATTN_CHUNK(&Ks[0][0], &Vt[0][0], &Ks[1][0], &Vt[1][0], c0);
        ATTN_CHUNK(&Ks[1][0], &Vt[1][0], &Ks[0][0], &Vt[0][0], c0 + 64);
    }
#undef ATTN_CHUNK

    float rl = __builtin_amdgcn_rcpf(l);
    size_t yrow = ((size_t)b * T_ + q0 + (wid << 4) + l15) * E_ + h * 64;
#pragma unroll
    for (int dt = 0; dt < 4; dt++) {
        ushort4 w;
        w.x = f2bf(o[dt][0] * rl); w.y = f2bf(o[dt][1] * rl);
        w.z = f2bf(o[dt][2] * rl); w.w = f2bf(o[dt][3] * rl);
        *(ushort4*)&y[yrow + (dt << 4) + (quad << 2)] = w;
    }
}

// ---------------------------------------------------------------------------
extern "C" void kernel_launch(void* const* d_in, const int* in_sizes, int n_in,
                              void* d_out, int out_size, void* d_ws, size_t ws_size,
                              hipStream_t stream) {
    const float* x_in  = (const float*)d_in[0];
    const float* Wqkv  = (const float*)d_in[1];
    const float* bqkv  = (const float*)d_in[2];
    const float* Wproj = (const float*)d_in[3];
    const float* bproj = (const float*)d_in[4];
    const float* W1    = (const float*)d_in[5];
    const float* b1    = (const float*)d_in[6];
    const float* W2    = (const float*)d_in[7];
    const float* b2    = (const float*)d_in[8];
    float* out = (float*)d_out;

    // workspace (bf16 elements), ~101 MB
    u16* WT   = (u16*)d_ws;            // 12,582,912
    u16* qkvb = WT   + 12582912;       // 12,582,912
    u16* yb   = qkvb + 12582912;       //  4,194,304
    u16* hb   = yb   + 4194304;        // 16,777,216
    u16* xb   = hb   + 16777216;       //  4,194,304

    convert_kernel<<<4096, 256, 0, stream>>>(x_in, xb, M_ * E_ / 4);

    for (int l = 0; l < L_; l++) {
        transpose_weights<<<12288, 256, 0, stream>>>(
            Wqkv + (size_t)l * E_ * 3 * E_, Wproj + (size_t)l * E_ * E_,
            W1 + (size_t)l * E_ * FF_, W2 + (size_t)l * FF_ * E_, WT);

        const float* xcur = (l == 0) ? x_in : out;

        // qkv = x @ Wqkv + bqkv (q cols pre-scaled by QS) -> bf16
        gemm_kernel<0><<<dim3(24, 32), 256, 0, stream>>>(
            xb, WT, bqkv + l * 3 * E_, qkvb, M_, 3 * E_, E_);

        attn_kernel<<<dim3(T_ / 64, H_, B_), 256, 0, stream>>>(qkvb, yb);

        // x = x + y @ Wproj + bproj -> f32 out, bf16 xb
        gemm_n64<<<dim3(16, 32), 256, 0, stream>>>(
            yb, WT + 3145728, bproj + l * E_, xcur, out, xb, M_, E_, E_);

        // h = gelu(x @ W1 + b1) -> bf16
        gemm_kernel<2><<<dim3(32, 32), 256, 0, stream>>>(
            xb, WT + 4194304, b1 + l * FF_, hb, M_, FF_, E_);

        // x = x + h @ W2 + b2 -> f32 out, bf16 xb (next layer's input)
        gemm_n64<<<dim3(16, 32), 256, 0, stream>>>(
            hb, WT + 8388608, b2 + l * E_, out, out, xb, M_, E_, FF_);
    }
}